// Round 1
// baseline (241.228 us; speedup 1.0000x reference)
//
#include <hip/hip_runtime.h>
#include <cstdint>
#include <cstddef>

// Problem constants (match reference setup_inputs)
#define NB   8          // batch
#define RDIM 1024
#define CDIM 1024
#define PB   (RDIM * CDIM)   // pixels per batch = 1M (2^20)
#define NI   16              // MAX_INSTANCES

// ---------------------------------------------------------------------------
// Kernel A: per-(batch,instance) valid-pixel histogram + (optionally) pack
// gt|mask into a uint8 map so the main pass reads 8 MB instead of 64 MB.
// LDS counters are replicated 4x (stride 17 to spread banks) to cut
// same-address LDS-atomic serialization; one global atomicAdd per (block,inst).
// ---------------------------------------------------------------------------
__global__ __launch_bounds__(256) void count_pack_kernel(
    const int* __restrict__ nz, const int* __restrict__ gt,
    uint8_t* __restrict__ gt8, int* __restrict__ counts)
{
    __shared__ int s[68];   // 4 replicas, stride 17
    const int b = blockIdx.y;
    for (int i = threadIdx.x; i < 68; i += blockDim.x) s[i] = 0;
    __syncthreads();

    const int rep = (threadIdx.x & 3) * 17;
    const int* nzb = nz + (size_t)b * PB;
    const int* gtb = gt + (size_t)b * PB;
    uint8_t* g8b = gt8 ? gt8 + (size_t)b * PB : nullptr;

    const int n4 = PB / 4;
    for (int i = blockIdx.x * blockDim.x + threadIdx.x; i < n4;
         i += gridDim.x * blockDim.x) {
        int4 nzv = ((const int4*)nzb)[i];
        int4 gv  = ((const int4*)gtb)[i];
        const int m0 = (nzv.x > 0) & (gv.x > 0);
        const int m1 = (nzv.y > 0) & (gv.y > 0);
        const int m2 = (nzv.z > 0) & (gv.z > 0);
        const int m3 = (nzv.w > 0) & (gv.w > 0);
        if (m0) atomicAdd(&s[rep + gv.x], 1);
        if (m1) atomicAdd(&s[rep + gv.y], 1);
        if (m2) atomicAdd(&s[rep + gv.z], 1);
        if (m3) atomicAdd(&s[rep + gv.w], 1);
        if (g8b) {
            uchar4 o;
            o.x = (uint8_t)(gv.x | (m0 << 7));
            o.y = (uint8_t)(gv.y | (m1 << 7));
            o.z = (uint8_t)(gv.z | (m2 << 7));
            o.w = (uint8_t)(gv.w | (m3 << 7));
            ((uchar4*)g8b)[i] = o;
        }
    }
    __syncthreads();
    if (threadIdx.x < NI) {
        int sum = s[threadIdx.x] + s[17 + threadIdx.x] +
                  s[34 + threadIdx.x] + s[51 + threadIdx.x];
        if (sum) atomicAdd(&counts[b * NI + threadIdx.x], sum);
    }
}

// ---------------------------------------------------------------------------
// Kernel B: main per-pixel pass.
//   pixel_weight  = w * sigmoid(pixel_pred)
//   offset_weight = (agree * w) * offset_pred      (both channels)
// PACKED=true reads the uint8 gt|mask map; false reads raw int32 inputs.
// rintf == round-half-to-even == np.round (critical for `agree` parity).
// ---------------------------------------------------------------------------
template <bool PACKED>
__global__ __launch_bounds__(256) void cluster_kernel(
    const float* __restrict__ pp, const float* __restrict__ op,
    const uint8_t* __restrict__ gt8,
    const int* __restrict__ nz, const int* __restrict__ gt,
    const int* __restrict__ counts, float* __restrict__ out)
{
    __shared__ float inv[NI];
    const int b = blockIdx.y;
    if (threadIdx.x < NI) {
        int c = counts[b * NI + threadIdx.x];
        inv[threadIdx.x] = 1.0f / (float)(c > 1 ? c : 1);
    }
    __syncthreads();

    const uint8_t* g8b = PACKED ? gt8 + (size_t)b * PB : nullptr;
    const int*     gtb = gt + (size_t)b * PB;
    const int*     nzb = nz + (size_t)b * PB;
    const float*   ppb = pp + (size_t)b * PB;
    const float*   dyb = op + (size_t)b * 2 * PB;
    const float*   dxb = dyb + PB;
    float* pwb  = out + (size_t)b * PB;
    float* owyb = out + (size_t)NB * PB + (size_t)b * 2 * PB;
    float* owxb = owyb + PB;

    const int n4 = PB / 4;
    for (int i = blockIdx.x * blockDim.x + threadIdx.x; i < n4;
         i += gridDim.x * blockDim.x) {
        const int p = i * 4;
        const float rf  = (float)(p >> 10);          // row
        const float cf0 = (float)(p & (CDIM - 1));   // first col of the quad

        float4 ppv = ((const float4*)ppb)[i];
        float4 dyv = ((const float4*)dyb)[i];
        float4 dxv = ((const float4*)dxb)[i];

        int   gs[4];
        int   ms[4];
        if (PACKED) {
            uchar4 gv = ((const uchar4*)g8b)[i];
            const int raw[4] = {gv.x, gv.y, gv.z, gv.w};
            #pragma unroll
            for (int j = 0; j < 4; ++j) { gs[j] = raw[j] & 0x7f; ms[j] = raw[j] >> 7; }
        } else {
            int4 gv  = ((const int4*)gtb)[i];
            int4 nzv = ((const int4*)nzb)[i];
            const int g_[4] = {gv.x, gv.y, gv.z, gv.w};
            const int n_[4] = {nzv.x, nzv.y, nzv.z, nzv.w};
            #pragma unroll
            for (int j = 0; j < 4; ++j) { gs[j] = g_[j]; ms[j] = (n_[j] > 0) & (g_[j] > 0); }
        }

        const float pps[4] = {ppv.x, ppv.y, ppv.z, ppv.w};
        const float dys[4] = {dyv.x, dyv.y, dyv.z, dyv.w};
        const float dxs[4] = {dxv.x, dxv.y, dxv.z, dxv.w};
        float pw[4], oy[4], ox[4];

        #pragma unroll
        for (int j = 0; j < 4; ++j) {
            const float w = ms[j] ? inv[gs[j]] : 0.0f;
            // target pixel: round-half-even, clip to image
            float ty = fminf(fmaxf(rintf(rf + dys[j]), 0.0f), (float)(RDIM - 1));
            float tx = fminf(fmaxf(rintf(cf0 + (float)j + dxs[j]), 0.0f), (float)(CDIM - 1));
            const int ti = (int)ty * CDIM + (int)tx;
            int tg;
            if (PACKED) tg = g8b[ti] & 0x7f;
            else        tg = gtb[ti];
            const float aw = (ms[j] && (tg == gs[j])) ? w : 0.0f;
            pw[j] = w * (1.0f / (1.0f + __expf(-pps[j])));
            oy[j] = aw * dys[j];
            ox[j] = aw * dxs[j];
        }

        ((float4*)pwb)[i]  = make_float4(pw[0], pw[1], pw[2], pw[3]);
        ((float4*)owyb)[i] = make_float4(oy[0], oy[1], oy[2], oy[3]);
        ((float4*)owxb)[i] = make_float4(ox[0], ox[1], ox[2], ox[3]);
    }
}

extern "C" void kernel_launch(void* const* d_in, const int* in_sizes, int n_in,
                              void* d_out, int out_size, void* d_ws, size_t ws_size,
                              hipStream_t stream) {
    // setup_inputs order: non_zeros_map, pixel_pred, offset_pred, pixel_gt
    const int*   nz = (const int*)d_in[0];
    const float* pp = (const float*)d_in[1];
    const float* op = (const float*)d_in[2];
    const int*   gt = (const int*)d_in[3];
    float* out = (float*)d_out;

    int* counts = (int*)d_ws;                       // NB*NI ints at ws[0]
    const size_t need = 1024 + (size_t)NB * PB;     // counts (padded) + gt8 map
    const bool packed = ws_size >= need;
    uint8_t* gt8 = packed ? (uint8_t*)d_ws + 1024 : nullptr;

    hipMemsetAsync(counts, 0, NB * NI * sizeof(int), stream);

    dim3 blkA(256), grdA(512, NB);   // 2 int4-groups per thread
    count_pack_kernel<<<grdA, blkA, 0, stream>>>(nz, gt, gt8, counts);

    dim3 blkB(256), grdB(1024, NB);  // 1 float4-group per thread
    if (packed)
        cluster_kernel<true><<<grdB, blkB, 0, stream>>>(pp, op, gt8, nz, gt, counts, out);
    else
        cluster_kernel<false><<<grdB, blkB, 0, stream>>>(pp, op, nullptr, nz, gt, counts, out);
}

// Round 2
// 230.674 us; speedup vs baseline: 1.0457x; 1.0457x over previous
//
#include <hip/hip_runtime.h>
#include <cstdint>
#include <cstddef>

// Problem constants (match reference setup_inputs)
#define NB   8               // batch
#define RDIM 1024
#define CDIM 1024
#define PB   (RDIM * CDIM)   // pixels per batch = 1M
#define NI   16              // MAX_INSTANCES

typedef int     i32x4 __attribute__((ext_vector_type(4)));
typedef float   f32x4 __attribute__((ext_vector_type(4)));
typedef uint8_t u8x4  __attribute__((ext_vector_type(4)));

// ---------------------------------------------------------------------------
// Kernel A: per-(batch,instance) valid-pixel histogram via wave-ballot
// popcount (NO per-pixel atomics), + pack gt|mask into a uint8 map so the
// main pass reads 8 MB instead of 64 MB.
//   - nz/gt are streamed once -> non-temporal loads (keep L2 for gt8)
//   - gt8 store is cached (kernel B re-reads it immediately)
//   - wc[id] is wave-uniform (ballot result identical on all lanes) -> the
//     accumulate lowers to scalar s_bcnt1/s_add; 15 bins, bin 0 never needed
//     (mask requires gt>0)
// ---------------------------------------------------------------------------
__global__ __launch_bounds__(256) void count_pack_kernel(
    const int* __restrict__ nz, const int* __restrict__ gt,
    uint8_t* __restrict__ gt8, int* __restrict__ counts)
{
    __shared__ unsigned s[4 * NI];           // 4 waves x 16 bins
    const int b    = blockIdx.y;
    const int lane = threadIdx.x & 63;
    const int wv   = threadIdx.x >> 6;
    const i32x4* nzb = (const i32x4*)(nz + (size_t)b * PB);
    const i32x4* gtb = (const i32x4*)(gt + (size_t)b * PB);
    u8x4* g8b = gt8 ? (u8x4*)(gt8 + (size_t)b * PB) : nullptr;

    unsigned wc[NI];
    #pragma unroll
    for (int k = 0; k < NI; ++k) wc[k] = 0;

    const int n4 = PB / 4;
    for (int i = blockIdx.x * blockDim.x + threadIdx.x; i < n4;
         i += gridDim.x * blockDim.x) {
        i32x4 nzv = __builtin_nontemporal_load(&nzb[i]);
        i32x4 gv  = __builtin_nontemporal_load(&gtb[i]);
        int gm[4];
        u8x4 o;
        #pragma unroll
        for (int j = 0; j < 4; ++j) {
            const int g = gv[j];
            const int m = (nzv[j] > 0) & (g > 0);
            gm[j] = m ? g : 0;                       // 0 = contributes nowhere
            o[j]  = (uint8_t)(g | (m << 7));
        }
        if (g8b) g8b[i] = o;                          // cached store
        #pragma unroll
        for (int j = 0; j < 4; ++j) {
            #pragma unroll
            for (int id = 1; id < NI; ++id) {
                unsigned long long bal = __ballot(gm[j] == id);
                wc[id] += (unsigned)__popcll(bal);    // wave-uniform scalar add
            }
        }
    }
    if (lane == 0) {
        #pragma unroll
        for (int id = 1; id < NI; ++id) s[wv * NI + id] = wc[id];
    }
    __syncthreads();
    if (threadIdx.x >= 1 && threadIdx.x < NI) {
        unsigned sum = s[threadIdx.x] + s[NI + threadIdx.x] +
                       s[2 * NI + threadIdx.x] + s[3 * NI + threadIdx.x];
        if (sum) atomicAdd((unsigned*)&counts[b * NI + threadIdx.x], sum);
    }
}

// ---------------------------------------------------------------------------
// Kernel B: main per-pixel pass (single iteration per thread; grid covers
// exactly PB/4 quads per batch).
//   pixel_weight  = w * sigmoid(pixel_pred)
//   offset_weight = (agree * w) * offset_pred
// rintf == round-half-to-even == np.round (critical for `agree` parity).
// Streamed data (pp, dy, dx, out) uses non-temporal hints; the gather map
// (gt8) stays cached. XCD band swizzle keeps the +-12px gather in-L2.
// ---------------------------------------------------------------------------
template <bool PACKED>
__global__ __launch_bounds__(256) void cluster_kernel(
    const float* __restrict__ pp, const float* __restrict__ op,
    const uint8_t* __restrict__ gt8,
    const int* __restrict__ nz, const int* __restrict__ gt,
    const int* __restrict__ counts, float* __restrict__ out)
{
    __shared__ float inv[NI];
    const int b = blockIdx.y;
    if (threadIdx.x < NI) {
        int c = counts[b * NI + threadIdx.x];
        inv[threadIdx.x] = 1.0f / (float)(c > 1 ? c : 1);
    }
    __syncthreads();

    // XCD band swizzle: dispatch round-robins blockIdx over 8 XCDs; remap so
    // XCD x owns logical blocks [x*128, (x+1)*128) = a contiguous 512-row band.
    const int nbx = gridDim.x;                     // 1024
    const int p   = blockIdx.x;
    const int bx  = (p & 7) * (nbx >> 3) + (p >> 3);
    const int i   = bx * blockDim.x + threadIdx.x; // quad index in [0, PB/4)

    const uint8_t* g8b = PACKED ? gt8 + (size_t)b * PB : nullptr;
    const int*     gtb = gt + (size_t)b * PB;
    const int*     nzb = nz + (size_t)b * PB;
    const float*   ppb = pp + (size_t)b * PB;
    const float*   dyb = op + (size_t)b * 2 * PB;
    const float*   dxb = dyb + PB;
    float* pwb  = out + (size_t)b * PB;
    float* owyb = out + (size_t)NB * PB + (size_t)b * 2 * PB;
    float* owxb = owyb + PB;

    const int   pix = i * 4;
    const float rf  = (float)(pix >> 10);          // row
    const float cf0 = (float)(pix & (CDIM - 1));   // first col of the quad

    f32x4 ppv = __builtin_nontemporal_load((const f32x4*)ppb + i);
    f32x4 dyv = __builtin_nontemporal_load((const f32x4*)dyb + i);
    f32x4 dxv = __builtin_nontemporal_load((const f32x4*)dxb + i);

    int gs[4], ms[4];
    if (PACKED) {
        u8x4 gv = *((const u8x4*)g8b + i);
        #pragma unroll
        for (int j = 0; j < 4; ++j) { gs[j] = gv[j] & 0x7f; ms[j] = gv[j] >> 7; }
    } else {
        i32x4 gv  = *((const i32x4*)gtb + i);
        i32x4 nzv = *((const i32x4*)nzb + i);
        #pragma unroll
        for (int j = 0; j < 4; ++j) { gs[j] = gv[j]; ms[j] = (nzv[j] > 0) & (gv[j] > 0); }
    }

    f32x4 pwv, oyv, oxv;
    #pragma unroll
    for (int j = 0; j < 4; ++j) {
        const float dy = dyv[j], dx = dxv[j];
        const float w  = ms[j] ? inv[gs[j]] : 0.0f;
        // target pixel: round-half-even, clip to image
        float ty = fminf(fmaxf(rintf(rf + dy), 0.0f), (float)(RDIM - 1));
        float tx = fminf(fmaxf(rintf(cf0 + (float)j + dx), 0.0f), (float)(CDIM - 1));
        const int ti = (int)ty * CDIM + (int)tx;
        int tg;
        if (PACKED) tg = g8b[ti] & 0x7f;
        else        tg = gtb[ti];
        const float aw = (ms[j] && (tg == gs[j])) ? w : 0.0f;
        pwv[j] = w * (1.0f / (1.0f + __expf(-ppv[j])));
        oyv[j] = aw * dy;
        oxv[j] = aw * dx;
    }

    __builtin_nontemporal_store(pwv, (f32x4*)pwb  + i);
    __builtin_nontemporal_store(oyv, (f32x4*)owyb + i);
    __builtin_nontemporal_store(oxv, (f32x4*)owxb + i);
}

extern "C" void kernel_launch(void* const* d_in, const int* in_sizes, int n_in,
                              void* d_out, int out_size, void* d_ws, size_t ws_size,
                              hipStream_t stream) {
    // setup_inputs order: non_zeros_map, pixel_pred, offset_pred, pixel_gt
    const int*   nz = (const int*)d_in[0];
    const float* pp = (const float*)d_in[1];
    const float* op = (const float*)d_in[2];
    const int*   gt = (const int*)d_in[3];
    float* out = (float*)d_out;

    int* counts = (int*)d_ws;                       // NB*NI ints at ws[0]
    const size_t need = 1024 + (size_t)NB * PB;     // counts (padded) + gt8 map
    const bool packed = ws_size >= need;
    uint8_t* gt8 = packed ? (uint8_t*)d_ws + 1024 : nullptr;

    hipMemsetAsync(counts, 0, NB * NI * sizeof(int), stream);

    dim3 blkA(256), grdA(256, NB);   // 4 int4-quads per thread
    count_pack_kernel<<<grdA, blkA, 0, stream>>>(nz, gt, gt8, counts);

    dim3 blkB(256), grdB(1024, NB);  // exactly 1 float4-quad per thread
    if (packed)
        cluster_kernel<true><<<grdB, blkB, 0, stream>>>(pp, op, gt8, nz, gt, counts, out);
    else
        cluster_kernel<false><<<grdB, blkB, 0, stream>>>(pp, op, nullptr, nz, gt, counts, out);
}

// Round 3
// 229.071 us; speedup vs baseline: 1.0531x; 1.0070x over previous
//
#include <hip/hip_runtime.h>
#include <cstdint>
#include <cstddef>

// Problem constants (match reference setup_inputs)
#define NB   8               // batch
#define RDIM 1024
#define CDIM 1024
#define PB   (RDIM * CDIM)   // pixels per batch = 1M
#define NI   16              // MAX_INSTANCES

typedef int     i32x4 __attribute__((ext_vector_type(4)));
typedef float   f32x4 __attribute__((ext_vector_type(4)));
typedef uint8_t u8x4  __attribute__((ext_vector_type(4)));

// ---------------------------------------------------------------------------
// Kernel A: per-(batch,instance) valid-pixel histogram via wave-ballot
// popcount (no per-pixel atomics) + pack gt|mask into a uint8 map (8 MB)
// so the main pass reads 8 MB instead of 64 MB. ~15 us, near its 64 MB
// BW floor — left structurally unchanged.
// ---------------------------------------------------------------------------
__global__ __launch_bounds__(256) void count_pack_kernel(
    const int* __restrict__ nz, const int* __restrict__ gt,
    uint8_t* __restrict__ gt8, int* __restrict__ counts)
{
    __shared__ unsigned s[4 * NI];           // 4 waves x 16 bins
    const int b    = blockIdx.y;
    const int lane = threadIdx.x & 63;
    const int wv   = threadIdx.x >> 6;
    const i32x4* nzb = (const i32x4*)(nz + (size_t)b * PB);
    const i32x4* gtb = (const i32x4*)(gt + (size_t)b * PB);
    u8x4* g8b = gt8 ? (u8x4*)(gt8 + (size_t)b * PB) : nullptr;

    unsigned wc[NI];
    #pragma unroll
    for (int k = 0; k < NI; ++k) wc[k] = 0;

    const int n4 = PB / 4;
    for (int i = blockIdx.x * blockDim.x + threadIdx.x; i < n4;
         i += gridDim.x * blockDim.x) {
        i32x4 nzv = __builtin_nontemporal_load(&nzb[i]);
        i32x4 gv  = __builtin_nontemporal_load(&gtb[i]);
        int gm[4];
        u8x4 o;
        #pragma unroll
        for (int j = 0; j < 4; ++j) {
            const int g = gv[j];
            const int m = (nzv[j] > 0) & (g > 0);
            gm[j] = m ? g : 0;                       // 0 = contributes nowhere
            o[j]  = (uint8_t)(g | (m << 7));
        }
        if (g8b) g8b[i] = o;                          // cached store (B re-reads)
        #pragma unroll
        for (int j = 0; j < 4; ++j) {
            #pragma unroll
            for (int id = 1; id < NI; ++id) {
                unsigned long long bal = __ballot(gm[j] == id);
                wc[id] += (unsigned)__popcll(bal);    // wave-uniform scalar add
            }
        }
    }
    if (lane == 0) {
        #pragma unroll
        for (int id = 1; id < NI; ++id) s[wv * NI + id] = wc[id];
    }
    __syncthreads();
    if (threadIdx.x >= 1 && threadIdx.x < NI) {
        unsigned sum = s[threadIdx.x] + s[NI + threadIdx.x] +
                       s[2 * NI + threadIdx.x] + s[3 * NI + threadIdx.x];
        if (sum) atomicAdd((unsigned*)&counts[b * NI + threadIdx.x], sum);
    }
}

// ---------------------------------------------------------------------------
// Kernel B: main per-pixel pass, 4 quads per thread, software-pipelined.
//   - a block owns 1024 consecutive quads = 4 rows; thread t handles quads
//     {base+t, +256, +512, +768} = same column in 4 adjacent rows (its
//     gathers share cache lines)
//   - all 8 offset loads issued FIRST (head of the longest dep chain),
//     then pp + own-map loads, then the 16 byte-gathers, then compute
//   - streamed data uses non-temporal hints; the gather map stays cached
//   - XCD band swizzle: each XCD owns a contiguous 128-row band per batch
//     -> gather working set ~1 MB per XCD L2
// rintf == round-half-to-even == np.round (critical for `agree` parity).
// ---------------------------------------------------------------------------
template <bool PACKED>
__global__ __launch_bounds__(256) void cluster_kernel(
    const float* __restrict__ pp, const float* __restrict__ op,
    const uint8_t* __restrict__ gt8,
    const int* __restrict__ nz, const int* __restrict__ gt,
    const int* __restrict__ counts, float* __restrict__ out)
{
    __shared__ float inv[NI];
    const int b = blockIdx.y;
    if (threadIdx.x < NI) {
        int c = counts[b * NI + threadIdx.x];
        inv[threadIdx.x] = 1.0f / (float)(c > 1 ? c : 1);
    }
    __syncthreads();

    // XCD band swizzle (gridDim.x = 256, 8 XCDs -> 32-block bands)
    const int nbx  = gridDim.x;
    const int p0   = blockIdx.x;
    const int bx   = (p0 & 7) * (nbx >> 3) + (p0 >> 3);
    const int base = bx * 1024 + threadIdx.x;      // first quad of this thread

    const uint8_t* g8b = PACKED ? gt8 + (size_t)b * PB : nullptr;
    const int*     gtb = gt + (size_t)b * PB;
    const int*     nzb = nz + (size_t)b * PB;
    const f32x4*   ppb = (const f32x4*)(pp + (size_t)b * PB);
    const f32x4*   dyb = (const f32x4*)(op + (size_t)b * 2 * PB);
    const f32x4*   dxb = dyb + PB / 4;
    f32x4* pwb  = (f32x4*)(out + (size_t)b * PB);
    f32x4* owyb = (f32x4*)(out + (size_t)NB * PB + (size_t)b * 2 * PB);
    f32x4* owxb = owyb + PB / 4;

    // ---- phase 1: issue every streaming load up front ----
    f32x4 dyv[4], dxv[4], ppv[4];
    #pragma unroll
    for (int u = 0; u < 4; ++u) dyv[u] = __builtin_nontemporal_load(dyb + base + 256 * u);
    #pragma unroll
    for (int u = 0; u < 4; ++u) dxv[u] = __builtin_nontemporal_load(dxb + base + 256 * u);
    #pragma unroll
    for (int u = 0; u < 4; ++u) ppv[u] = __builtin_nontemporal_load(ppb + base + 256 * u);

    int gs[4][4], ms[4][4];
    if (PACKED) {
        #pragma unroll
        for (int u = 0; u < 4; ++u) {
            u8x4 gv = *((const u8x4*)g8b + base + 256 * u);
            #pragma unroll
            for (int j = 0; j < 4; ++j) { gs[u][j] = gv[j] & 0x7f; ms[u][j] = gv[j] >> 7; }
        }
    } else {
        #pragma unroll
        for (int u = 0; u < 4; ++u) {
            i32x4 gv  = *((const i32x4*)gtb + base + 256 * u);
            i32x4 nzv = *((const i32x4*)nzb + base + 256 * u);
            #pragma unroll
            for (int j = 0; j < 4; ++j) { gs[u][j] = gv[j]; ms[u][j] = (nzv[j] > 0) & (gv[j] > 0); }
        }
    }

    // ---- phase 2: target indices + gathers ----
    int tg[4][4];
    #pragma unroll
    for (int u = 0; u < 4; ++u) {
        const int   pix = (base + 256 * u) * 4;
        const float rf  = (float)(pix >> 10);
        const float cf0 = (float)(pix & (CDIM - 1));
        #pragma unroll
        for (int j = 0; j < 4; ++j) {
            float ty = fminf(fmaxf(rintf(rf + dyv[u][j]), 0.0f), (float)(RDIM - 1));
            float tx = fminf(fmaxf(rintf(cf0 + (float)j + dxv[u][j]), 0.0f), (float)(CDIM - 1));
            const int ti = (int)ty * CDIM + (int)tx;
            tg[u][j] = PACKED ? (g8b[ti] & 0x7f) : gtb[ti];
        }
    }

    // ---- phase 3: compute + store ----
    #pragma unroll
    for (int u = 0; u < 4; ++u) {
        f32x4 pwv, oyv, oxv;
        #pragma unroll
        for (int j = 0; j < 4; ++j) {
            const float w  = ms[u][j] ? inv[gs[u][j]] : 0.0f;
            const float aw = (ms[u][j] && (tg[u][j] == gs[u][j])) ? w : 0.0f;
            pwv[j] = w * (1.0f / (1.0f + __expf(-ppv[u][j])));
            oyv[j] = aw * dyv[u][j];
            oxv[j] = aw * dxv[u][j];
        }
        __builtin_nontemporal_store(pwv, pwb  + base + 256 * u);
        __builtin_nontemporal_store(oyv, owyb + base + 256 * u);
        __builtin_nontemporal_store(oxv, owxb + base + 256 * u);
    }
}

extern "C" void kernel_launch(void* const* d_in, const int* in_sizes, int n_in,
                              void* d_out, int out_size, void* d_ws, size_t ws_size,
                              hipStream_t stream) {
    // setup_inputs order: non_zeros_map, pixel_pred, offset_pred, pixel_gt
    const int*   nz = (const int*)d_in[0];
    const float* pp = (const float*)d_in[1];
    const float* op = (const float*)d_in[2];
    const int*   gt = (const int*)d_in[3];
    float* out = (float*)d_out;

    int* counts = (int*)d_ws;                       // NB*NI ints at ws[0]
    const size_t need = 1024 + (size_t)NB * PB;     // counts (padded) + gt8 map
    const bool packed = ws_size >= need;
    uint8_t* gt8 = packed ? (uint8_t*)d_ws + 1024 : nullptr;

    hipMemsetAsync(counts, 0, NB * NI * sizeof(int), stream);

    dim3 blkA(256), grdA(256, NB);   // 4 int4-quads per thread
    count_pack_kernel<<<grdA, blkA, 0, stream>>>(nz, gt, gt8, counts);

    dim3 blkB(256), grdB(256, NB);   // 4 float4-quads per thread, pipelined
    if (packed)
        cluster_kernel<true><<<grdB, blkB, 0, stream>>>(pp, op, gt8, nz, gt, counts, out);
    else
        cluster_kernel<false><<<grdB, blkB, 0, stream>>>(pp, op, nullptr, nz, gt, counts, out);
}

// Round 4
// 227.463 us; speedup vs baseline: 1.0605x; 1.0071x over previous
//
#include <hip/hip_runtime.h>
#include <cstdint>
#include <cstddef>

// Problem constants (match reference setup_inputs)
#define NB   8               // batch
#define RDIM 1024
#define CDIM 1024
#define PB   (RDIM * CDIM)   // pixels per batch = 1M
#define NI   16              // MAX_INSTANCES

// Cluster-kernel geometry: 1024-thread blocks, 8 rows/block, LDS-staged
// gather window of 8 + 2*26 = 60 rows (61440 B, under the 64 KB static cap).
// Margin 26 covers |offset| up to 26 px; N(0,4)-distributed offsets max out
// ~23 over 8.4M samples; anything larger takes the (execz-skipped) global
// fallback path, so correctness holds for arbitrary offsets.
#define MARG  26
#define BROWS 8
#define WROWS (BROWS + 2 * MARG)   // 60

typedef int     i32x4 __attribute__((ext_vector_type(4)));
typedef float   f32x4 __attribute__((ext_vector_type(4)));
typedef uint8_t u8x4  __attribute__((ext_vector_type(4)));

// ---------------------------------------------------------------------------
// Kernel A: per-(batch,instance) valid-pixel histogram via wave-ballot
// popcount (no per-pixel atomics) + pack gt|mask into a uint8 map (8 MB).
// ~15 us, near its 64 MB read floor. Unchanged from R3.
// ---------------------------------------------------------------------------
__global__ __launch_bounds__(256) void count_pack_kernel(
    const int* __restrict__ nz, const int* __restrict__ gt,
    uint8_t* __restrict__ gt8, int* __restrict__ counts)
{
    __shared__ unsigned s[4 * NI];           // 4 waves x 16 bins
    const int b    = blockIdx.y;
    const int lane = threadIdx.x & 63;
    const int wv   = threadIdx.x >> 6;
    const i32x4* nzb = (const i32x4*)(nz + (size_t)b * PB);
    const i32x4* gtb = (const i32x4*)(gt + (size_t)b * PB);
    u8x4* g8b = gt8 ? (u8x4*)(gt8 + (size_t)b * PB) : nullptr;

    unsigned wc[NI];
    #pragma unroll
    for (int k = 0; k < NI; ++k) wc[k] = 0;

    const int n4 = PB / 4;
    for (int i = blockIdx.x * blockDim.x + threadIdx.x; i < n4;
         i += gridDim.x * blockDim.x) {
        i32x4 nzv = __builtin_nontemporal_load(&nzb[i]);
        i32x4 gv  = __builtin_nontemporal_load(&gtb[i]);
        int gm[4];
        u8x4 o;
        #pragma unroll
        for (int j = 0; j < 4; ++j) {
            const int g = gv[j];
            const int m = (nzv[j] > 0) & (g > 0);
            gm[j] = m ? g : 0;                       // 0 = contributes nowhere
            o[j]  = (uint8_t)(g | (m << 7));
        }
        if (g8b) g8b[i] = o;                          // cached store (B re-reads)
        #pragma unroll
        for (int j = 0; j < 4; ++j) {
            #pragma unroll
            for (int id = 1; id < NI; ++id) {
                unsigned long long bal = __ballot(gm[j] == id);
                wc[id] += (unsigned)__popcll(bal);    // wave-uniform scalar add
            }
        }
    }
    if (lane == 0) {
        #pragma unroll
        for (int id = 1; id < NI; ++id) s[wv * NI + id] = wc[id];
    }
    __syncthreads();
    if (threadIdx.x >= 1 && threadIdx.x < NI) {
        unsigned sum = s[threadIdx.x] + s[NI + threadIdx.x] +
                       s[2 * NI + threadIdx.x] + s[3 * NI + threadIdx.x];
        if (sum) atomicAdd((unsigned*)&counts[b * NI + threadIdx.x], sum);
    }
}

// ---------------------------------------------------------------------------
// Kernel B (packed path): LDS-staged gather.
//  - block = 1024 threads, owns 8 consecutive rows (2048 quads, 2/thread)
//  - stages the 60-row gt8 window into LDS; gathers become ds_read_u8
//    (random addr ~2-way bank alias = free) instead of 64-line L1 probes
//  - own-pixel map bytes also come from LDS (no global map re-read)
//  - out-of-window targets (clamped far jumps / >26 px offsets) take a
//    predicated global fallback, normally execz-skipped
//  - streamed pp/dy/dx use NT loads; out uses NT stores
//  - XCD band swizzle keeps overlapping windows on one XCD's L2
// rintf == round-half-to-even == np.round (critical for `agree` parity).
// ---------------------------------------------------------------------------
__global__ __launch_bounds__(1024, 8) void cluster_lds_kernel(
    const float* __restrict__ pp, const float* __restrict__ op,
    const uint8_t* __restrict__ gt8,
    const int* __restrict__ counts, float* __restrict__ out)
{
    __shared__ __align__(16) uint8_t sg[WROWS * CDIM];   // 61440 B
    __shared__ float inv[NI];

    const int b   = blockIdx.y;
    const int tid = threadIdx.x;

    // XCD band swizzle (gridDim.x = 128, 8 XCDs -> 16-block bands)
    const int nbx = gridDim.x;
    const int p0  = blockIdx.x;
    const int bx  = (p0 & 7) * (nbx >> 3) + (p0 >> 3);

    const int r0 = bx * BROWS;
    const int w0 = (r0 - MARG) > 0 ? (r0 - MARG) : 0;
    int w1 = r0 + BROWS + MARG; if (w1 > RDIM) w1 = RDIM;

    const uint8_t* g8b = gt8 + (size_t)b * PB;

    if (tid < NI) {
        int c = counts[b * NI + tid];
        inv[tid] = 1.0f / (float)(c > 1 ? c : 1);
    }
    // stage rows [w0, w1) of the map (16 B per thread-iteration, coalesced)
    {
        const int nb16 = ((w1 - w0) << 10) >> 4;
        const i32x4* src = (const i32x4*)(g8b + ((size_t)w0 << 10));
        i32x4* dst = (i32x4*)sg;
        for (int k = tid; k < nb16; k += 1024) dst[k] = src[k];
    }
    __syncthreads();

    const f32x4* ppb = (const f32x4*)(pp + (size_t)b * PB);
    const f32x4* dyb = (const f32x4*)(op + (size_t)b * 2 * PB);
    const f32x4* dxb = dyb + PB / 4;
    f32x4* pwb  = (f32x4*)(out + (size_t)b * PB);
    f32x4* owyb = (f32x4*)(out + (size_t)NB * PB + (size_t)b * 2 * PB);
    f32x4* owxb = owyb + PB / 4;

    const int q0 = bx * (BROWS * CDIM / 4) + tid;   // first of 2 quads

    // issue all streaming loads up front
    f32x4 dyv[2], dxv[2], ppv[2];
    #pragma unroll
    for (int u = 0; u < 2; ++u) dyv[u] = __builtin_nontemporal_load(dyb + q0 + 1024 * u);
    #pragma unroll
    for (int u = 0; u < 2; ++u) dxv[u] = __builtin_nontemporal_load(dxb + q0 + 1024 * u);
    #pragma unroll
    for (int u = 0; u < 2; ++u) ppv[u] = __builtin_nontemporal_load(ppb + q0 + 1024 * u);

    // own map bytes from LDS (own rows are always inside the window)
    uint32_t own[2];
    #pragma unroll
    for (int u = 0; u < 2; ++u) {
        const int pix = (q0 + 1024 * u) * 4;
        const int r = pix >> 10, c = pix & (CDIM - 1);
        own[u] = *(const uint32_t*)&sg[((r - w0) << 10) + c];
    }

    #pragma unroll
    for (int u = 0; u < 2; ++u) {
        const int   pix = (q0 + 1024 * u) * 4;
        const float rf  = (float)(pix >> 10);
        const float cf0 = (float)(pix & (CDIM - 1));
        f32x4 pwv, oyv, oxv;
        #pragma unroll
        for (int j = 0; j < 4; ++j) {
            const int gbyte = (own[u] >> (8 * j)) & 0xff;
            const int gs = gbyte & 0x7f;
            const int ms = gbyte >> 7;
            const float dy = dyv[u][j], dx = dxv[u][j];
            const float tyf = fminf(fmaxf(rintf(rf + dy), 0.0f), (float)(RDIM - 1));
            const float txf = fminf(fmaxf(rintf(cf0 + (float)j + dx), 0.0f), (float)(CDIM - 1));
            const int ty = (int)tyf, tx = (int)txf;
            int tg;
            if (ty >= w0 && ty < w1)
                tg = sg[((ty - w0) << 10) + tx] & 0x7f;     // LDS gather
            else
                tg = g8b[(ty << 10) + tx] & 0x7f;           // rare fallback
            const float w  = ms ? inv[gs] : 0.0f;
            const float aw = (ms && (tg == gs)) ? w : 0.0f;
            pwv[j] = w * (1.0f / (1.0f + __expf(-ppv[u][j])));
            oyv[j] = aw * dy;
            oxv[j] = aw * dx;
        }
        __builtin_nontemporal_store(pwv, pwb  + q0 + 1024 * u);
        __builtin_nontemporal_store(oyv, owyb + q0 + 1024 * u);
        __builtin_nontemporal_store(oxv, owxb + q0 + 1024 * u);
    }
}

// ---------------------------------------------------------------------------
// Fallback (ws too small for the packed map): R2-style direct kernel.
// ---------------------------------------------------------------------------
__global__ __launch_bounds__(256) void cluster_plain_kernel(
    const float* __restrict__ pp, const float* __restrict__ op,
    const int* __restrict__ nz, const int* __restrict__ gt,
    const int* __restrict__ counts, float* __restrict__ out)
{
    __shared__ float inv[NI];
    const int b = blockIdx.y;
    if (threadIdx.x < NI) {
        int c = counts[b * NI + threadIdx.x];
        inv[threadIdx.x] = 1.0f / (float)(c > 1 ? c : 1);
    }
    __syncthreads();
    const int i = blockIdx.x * blockDim.x + threadIdx.x;

    const int*   gtb = gt + (size_t)b * PB;
    const int*   nzb = nz + (size_t)b * PB;
    const f32x4* ppb = (const f32x4*)(pp + (size_t)b * PB);
    const f32x4* dyb = (const f32x4*)(op + (size_t)b * 2 * PB);
    const f32x4* dxb = dyb + PB / 4;
    f32x4* pwb  = (f32x4*)(out + (size_t)b * PB);
    f32x4* owyb = (f32x4*)(out + (size_t)NB * PB + (size_t)b * 2 * PB);
    f32x4* owxb = owyb + PB / 4;

    const int   pix = i * 4;
    const float rf  = (float)(pix >> 10);
    const float cf0 = (float)(pix & (CDIM - 1));
    f32x4 ppv = ppb[i], dyv = dyb[i], dxv = dxb[i];
    i32x4 gv = *((const i32x4*)gtb + i), nzv = *((const i32x4*)nzb + i);

    f32x4 pwv, oyv, oxv;
    #pragma unroll
    for (int j = 0; j < 4; ++j) {
        const int gs = gv[j];
        const int ms = (nzv[j] > 0) & (gs > 0);
        float ty = fminf(fmaxf(rintf(rf + dyv[j]), 0.0f), (float)(RDIM - 1));
        float tx = fminf(fmaxf(rintf(cf0 + (float)j + dxv[j]), 0.0f), (float)(CDIM - 1));
        const int tg = gtb[(int)ty * CDIM + (int)tx];
        const float w  = ms ? inv[gs] : 0.0f;
        const float aw = (ms && (tg == gs)) ? w : 0.0f;
        pwv[j] = w * (1.0f / (1.0f + __expf(-ppv[j])));
        oyv[j] = aw * dyv[j];
        oxv[j] = aw * dxv[j];
    }
    pwb[i] = pwv; owyb[i] = oyv; owxb[i] = oxv;
}

extern "C" void kernel_launch(void* const* d_in, const int* in_sizes, int n_in,
                              void* d_out, int out_size, void* d_ws, size_t ws_size,
                              hipStream_t stream) {
    // setup_inputs order: non_zeros_map, pixel_pred, offset_pred, pixel_gt
    const int*   nz = (const int*)d_in[0];
    const float* pp = (const float*)d_in[1];
    const float* op = (const float*)d_in[2];
    const int*   gt = (const int*)d_in[3];
    float* out = (float*)d_out;

    int* counts = (int*)d_ws;                       // NB*NI ints at ws[0]
    const size_t need = 1024 + (size_t)NB * PB;     // counts (padded) + gt8 map
    const bool packed = ws_size >= need;
    uint8_t* gt8 = packed ? (uint8_t*)d_ws + 1024 : nullptr;

    hipMemsetAsync(counts, 0, NB * NI * sizeof(int), stream);

    dim3 blkA(256), grdA(256, NB);
    count_pack_kernel<<<grdA, blkA, 0, stream>>>(nz, gt, gt8, counts);

    if (packed) {
        dim3 blkB(1024), grdB(RDIM / BROWS / 1, NB);   // 128 x 8 blocks
        cluster_lds_kernel<<<dim3(128, NB), blkB, 0, stream>>>(pp, op, gt8, counts, out);
        (void)grdB;
    } else {
        dim3 blkB(256), grdB(1024, NB);
        cluster_plain_kernel<<<grdB, blkB, 0, stream>>>(pp, op, nz, gt, counts, out);
    }
}